// Round 1
// baseline (5552.117 us; speedup 1.0000x reference)
//
#include <hip/hip_runtime.h>
#include <hip/hip_bf16.h>

#define NNODES 100000
#define DFEAT 128

// ---------------------------------------------------------------------------
// Stage 1: conv = X   (eps = 0, so conv_X = X + agg; we seed the accumulator
// with X and scatter-add into it)
// ---------------------------------------------------------------------------
__global__ void init_conv(const float* __restrict__ X, float* __restrict__ conv,
                          long long n4) {
    long long i = (long long)blockIdx.x * blockDim.x + threadIdx.x;
    if (i < n4) {
        ((float4*)conv)[i] = ((const float4*)X)[i];
    }
}

// ---------------------------------------------------------------------------
// Stage 2: conv[dst[e]] += X[src[e]]  — 32 threads per edge, float4 per thread
// ---------------------------------------------------------------------------
__global__ void scatter_add(const float* __restrict__ X,
                            const int* __restrict__ dst,
                            const int* __restrict__ src,
                            float* __restrict__ conv, int nE) {
    long long g = (long long)blockIdx.x * blockDim.x + threadIdx.x;
    int e = (int)(g >> 5);
    if (e >= nE) return;
    int l = (int)(g & 31);
    int s = src[e];
    int d = dst[e];
    const float4 v = *(const float4*)(X + (size_t)s * DFEAT + l * 4);
    float* p = conv + (size_t)d * DFEAT + l * 4;
    unsafeAtomicAdd(p + 0, v.x);
    unsafeAtomicAdd(p + 1, v.y);
    unsafeAtomicAdd(p + 2, v.z);
    unsafeAtomicAdd(p + 3, v.w);
}

// ---------------------------------------------------------------------------
// Stages 3/4: C = relu(A @ W + b), A:[N,128] f32, W:[128,128], b:[128]
// 64 rows per block, 256 threads, per-thread 4x8 register tile.
// A-tile staged to LDS first => safe for C == A (in-place).
// LDS: sA 64x132 (pad +4 breaks ty bank aliasing) + sW 128x128 = ~97 KB.
// ---------------------------------------------------------------------------
__global__ __launch_bounds__(256, 1)
void gemm_relu(const float* __restrict__ A, const float* __restrict__ W,
               const float* __restrict__ bias, float* __restrict__ C, int N) {
    __shared__ float sA[64][132];
    __shared__ float sW[128][128];
    const int tid  = threadIdx.x;
    const int row0 = blockIdx.x * 64;

    // stage W: 128x128 floats = 4096 float4
    for (int i = tid; i < 128 * 32; i += 256) {
        int r = i >> 5, c = (i & 31) << 2;
        *(float4*)&sW[r][c] = *(const float4*)&W[r * 128 + c];
    }
    // stage A tile: 64x128 floats = 2048 float4 (zero-pad tail rows)
    for (int i = tid; i < 64 * 32; i += 256) {
        int r = i >> 5, c = (i & 31) << 2;
        float4 v = make_float4(0.f, 0.f, 0.f, 0.f);
        if (row0 + r < N) v = *(const float4*)&A[(size_t)(row0 + r) * 128 + c];
        *(float4*)&sA[r][c] = v;
    }
    __syncthreads();

    const int tx = tid & 15;   // 16 col-groups of 8
    const int ty = tid >> 4;   // 16 row-groups of 4
    float acc[4][8];
#pragma unroll
    for (int i = 0; i < 4; ++i)
#pragma unroll
        for (int j = 0; j < 8; ++j) acc[i][j] = 0.f;

#pragma unroll 8
    for (int k = 0; k < 128; ++k) {
        float4 w0 = *(const float4*)&sW[k][tx * 8];
        float4 w1 = *(const float4*)&sW[k][tx * 8 + 4];
        float a[4];
#pragma unroll
        for (int i = 0; i < 4; ++i) a[i] = sA[ty * 4 + i][k];
#pragma unroll
        for (int i = 0; i < 4; ++i) {
            acc[i][0] += a[i] * w0.x;
            acc[i][1] += a[i] * w0.y;
            acc[i][2] += a[i] * w0.z;
            acc[i][3] += a[i] * w0.w;
            acc[i][4] += a[i] * w1.x;
            acc[i][5] += a[i] * w1.y;
            acc[i][6] += a[i] * w1.z;
            acc[i][7] += a[i] * w1.w;
        }
    }

    float b[8];
#pragma unroll
    for (int j = 0; j < 8; ++j) b[j] = bias[tx * 8 + j];

#pragma unroll
    for (int i = 0; i < 4; ++i) {
        int row = row0 + ty * 4 + i;
        if (row < N) {
            float4 o0, o1;
            o0.x = fmaxf(acc[i][0] + b[0], 0.f);
            o0.y = fmaxf(acc[i][1] + b[1], 0.f);
            o0.z = fmaxf(acc[i][2] + b[2], 0.f);
            o0.w = fmaxf(acc[i][3] + b[3], 0.f);
            o1.x = fmaxf(acc[i][4] + b[4], 0.f);
            o1.y = fmaxf(acc[i][5] + b[5], 0.f);
            o1.z = fmaxf(acc[i][6] + b[6], 0.f);
            o1.w = fmaxf(acc[i][7] + b[7], 0.f);
            *(float4*)&C[(size_t)row * 128 + tx * 8]     = o0;
            *(float4*)&C[(size_t)row * 128 + tx * 8 + 4] = o1;
        }
    }
}

// ---------------------------------------------------------------------------
extern "C" void kernel_launch(void* const* d_in, const int* in_sizes, int n_in,
                              void* d_out, int out_size, void* d_ws, size_t ws_size,
                              hipStream_t stream) {
    const float* X    = (const float*)d_in[0];
    const int*   refA = (const int*)d_in[1];   // dst per edge
    const int*   refB = (const int*)d_in[2];   // src per edge
    const float* w1   = (const float*)d_in[3];
    const float* b1   = (const float*)d_in[4];
    const float* w2   = (const float*)d_in[5];
    const float* b2   = (const float*)d_in[6];
    float* out  = (float*)d_out;
    float* conv = (float*)d_ws;   // [N, 128] f32 accumulator, 51.2 MB

    const int nNodes = in_sizes[0] / DFEAT;    // 100000
    const int nE     = in_sizes[1];            // 3200000

    // 1) conv = X
    long long n4 = (long long)nNodes * (DFEAT / 4);
    init_conv<<<(int)((n4 + 255) / 256), 256, 0, stream>>>(X, conv, n4);

    // 2) conv[dst] += X[src]
    long long nThr = (long long)nE * 32;
    scatter_add<<<(int)((nThr + 255) / 256), 256, 0, stream>>>(X, refA, refB, conv, nE);

    // 3) conv = relu(conv @ w1 + b1)   (in-place, block-local via LDS staging)
    int gBlocks = (nNodes + 63) / 64;
    gemm_relu<<<gBlocks, 256, 0, stream>>>(conv, w1, b1, conv, nNodes);

    // 4) out = relu(conv @ w2 + b2)
    gemm_relu<<<gBlocks, 256, 0, stream>>>(conv, w2, b2, out, nNodes);
}

// Round 2
// 1027.235 us; speedup vs baseline: 5.4049x; 5.4049x over previous
//
#include <hip/hip_runtime.h>
#include <hip/hip_bf16.h>

#define NNODES 100000
#define DFEAT 128
#define SCAN_THREADS 1024

// ---------------------------------------------------------------------------
// CSR build stage 1: per-destination edge counts
// ---------------------------------------------------------------------------
__global__ void hist_kernel(const int* __restrict__ dst, int* __restrict__ counts,
                            int nE) {
    int i = blockIdx.x * blockDim.x + threadIdx.x;
    if (i < nE) atomicAdd(&counts[dst[i]], 1);
}

// ---------------------------------------------------------------------------
// CSR build stage 2: exclusive prefix sum of counts -> offsets (n+1), cursor
// Single workgroup of 1024 threads; each thread scans a contiguous chunk.
// ---------------------------------------------------------------------------
__global__ __launch_bounds__(SCAN_THREADS)
void scan_offsets(const int* __restrict__ counts, int* __restrict__ offsets,
                  int* __restrict__ cursor, int n) {
    __shared__ int part[SCAN_THREADS];
    const int tid = threadIdx.x;
    const int chunk = (n + SCAN_THREADS - 1) / SCAN_THREADS;
    const int lo = min(tid * chunk, n);
    const int hi = min(lo + chunk, n);

    int s = 0;
    for (int i = lo; i < hi; ++i) s += counts[i];
    part[tid] = s;
    __syncthreads();

    // Hillis-Steele inclusive scan over 1024 partials
    for (int d = 1; d < SCAN_THREADS; d <<= 1) {
        int v = (tid >= d) ? part[tid - d] : 0;
        __syncthreads();
        part[tid] += v;
        __syncthreads();
    }

    int run = (tid == 0) ? 0 : part[tid - 1];
    for (int i = lo; i < hi; ++i) {
        offsets[i] = run;
        cursor[i]  = run;
        run += counts[i];
    }
    if (tid == SCAN_THREADS - 1) offsets[n] = run;  // total = nE
}

// ---------------------------------------------------------------------------
// CSR build stage 3: scatter edge source ids into per-destination buckets
// ---------------------------------------------------------------------------
__global__ void build_csr(const int* __restrict__ dst, const int* __restrict__ src,
                          int* __restrict__ cursor, int* __restrict__ edge_src,
                          int nE) {
    int i = blockIdx.x * blockDim.x + threadIdx.x;
    if (i < nE) {
        int pos = atomicAdd(&cursor[dst[i]], 1);
        edge_src[pos] = src[i];
    }
}

// ---------------------------------------------------------------------------
// Pull aggregation: conv[n] = X[n] + sum_{e in csr(n)} X[edge_src[e]]
// 32 lanes per node (float4/lane covers 128 floats); 4-edge unroll for MLP.
// ---------------------------------------------------------------------------
__global__ __launch_bounds__(256)
void aggregate(const float* __restrict__ X, const int* __restrict__ offsets,
               const int* __restrict__ edge_src, float* __restrict__ conv,
               int nNodes) {
    long long g = (long long)blockIdx.x * blockDim.x + threadIdx.x;
    int node = (int)(g >> 5);
    if (node >= nNodes) return;
    int lane = (int)(g & 31);

    const float4* __restrict__ Xv = (const float4*)X;
    float4 acc = Xv[(size_t)node * 32 + lane];

    int e   = offsets[node];
    int end = offsets[node + 1];

    for (; e + 4 <= end; e += 4) {
        int s0 = edge_src[e + 0];
        int s1 = edge_src[e + 1];
        int s2 = edge_src[e + 2];
        int s3 = edge_src[e + 3];
        float4 v0 = Xv[(size_t)s0 * 32 + lane];
        float4 v1 = Xv[(size_t)s1 * 32 + lane];
        float4 v2 = Xv[(size_t)s2 * 32 + lane];
        float4 v3 = Xv[(size_t)s3 * 32 + lane];
        acc.x += v0.x; acc.y += v0.y; acc.z += v0.z; acc.w += v0.w;
        acc.x += v1.x; acc.y += v1.y; acc.z += v1.z; acc.w += v1.w;
        acc.x += v2.x; acc.y += v2.y; acc.z += v2.z; acc.w += v2.w;
        acc.x += v3.x; acc.y += v3.y; acc.z += v3.z; acc.w += v3.w;
    }
    for (; e < end; ++e) {
        int s = edge_src[e];
        float4 v = Xv[(size_t)s * 32 + lane];
        acc.x += v.x; acc.y += v.y; acc.z += v.z; acc.w += v.w;
    }

    ((float4*)conv)[(size_t)node * 32 + lane] = acc;
}

// ---------------------------------------------------------------------------
// C = relu(A @ W + b), A:[N,128] f32, W:[128,128], b:[128]
// 64 rows per block, 256 threads, per-thread 4x8 register tile.
// A staged to LDS before any write => safe in-place (C == A).
// ---------------------------------------------------------------------------
__global__ __launch_bounds__(256, 1)
void gemm_relu(const float* __restrict__ A, const float* __restrict__ W,
               const float* __restrict__ bias, float* __restrict__ C, int N) {
    __shared__ float sA[64][132];
    __shared__ float sW[128][128];
    const int tid  = threadIdx.x;
    const int row0 = blockIdx.x * 64;

    for (int i = tid; i < 128 * 32; i += 256) {
        int r = i >> 5, c = (i & 31) << 2;
        *(float4*)&sW[r][c] = *(const float4*)&W[r * 128 + c];
    }
    for (int i = tid; i < 64 * 32; i += 256) {
        int r = i >> 5, c = (i & 31) << 2;
        float4 v = make_float4(0.f, 0.f, 0.f, 0.f);
        if (row0 + r < N) v = *(const float4*)&A[(size_t)(row0 + r) * 128 + c];
        *(float4*)&sA[r][c] = v;
    }
    __syncthreads();

    const int tx = tid & 15;
    const int ty = tid >> 4;
    float acc[4][8];
#pragma unroll
    for (int i = 0; i < 4; ++i)
#pragma unroll
        for (int j = 0; j < 8; ++j) acc[i][j] = 0.f;

#pragma unroll 8
    for (int k = 0; k < 128; ++k) {
        float4 w0 = *(const float4*)&sW[k][tx * 8];
        float4 w1 = *(const float4*)&sW[k][tx * 8 + 4];
        float a[4];
#pragma unroll
        for (int i = 0; i < 4; ++i) a[i] = sA[ty * 4 + i][k];
#pragma unroll
        for (int i = 0; i < 4; ++i) {
            acc[i][0] += a[i] * w0.x;
            acc[i][1] += a[i] * w0.y;
            acc[i][2] += a[i] * w0.z;
            acc[i][3] += a[i] * w0.w;
            acc[i][4] += a[i] * w1.x;
            acc[i][5] += a[i] * w1.y;
            acc[i][6] += a[i] * w1.z;
            acc[i][7] += a[i] * w1.w;
        }
    }

    float b[8];
#pragma unroll
    for (int j = 0; j < 8; ++j) b[j] = bias[tx * 8 + j];

#pragma unroll
    for (int i = 0; i < 4; ++i) {
        int row = row0 + ty * 4 + i;
        if (row < N) {
            float4 o0, o1;
            o0.x = fmaxf(acc[i][0] + b[0], 0.f);
            o0.y = fmaxf(acc[i][1] + b[1], 0.f);
            o0.z = fmaxf(acc[i][2] + b[2], 0.f);
            o0.w = fmaxf(acc[i][3] + b[3], 0.f);
            o1.x = fmaxf(acc[i][4] + b[4], 0.f);
            o1.y = fmaxf(acc[i][5] + b[5], 0.f);
            o1.z = fmaxf(acc[i][6] + b[6], 0.f);
            o1.w = fmaxf(acc[i][7] + b[7], 0.f);
            *(float4*)&C[(size_t)row * 128 + tx * 8]     = o0;
            *(float4*)&C[(size_t)row * 128 + tx * 8 + 4] = o1;
        }
    }
}

// ---------------------------------------------------------------------------
extern "C" void kernel_launch(void* const* d_in, const int* in_sizes, int n_in,
                              void* d_out, int out_size, void* d_ws, size_t ws_size,
                              hipStream_t stream) {
    const float* X    = (const float*)d_in[0];
    const int*   refA = (const int*)d_in[1];   // dst per edge
    const int*   refB = (const int*)d_in[2];   // src per edge
    const float* w1   = (const float*)d_in[3];
    const float* b1   = (const float*)d_in[4];
    const float* w2   = (const float*)d_in[5];
    const float* b2   = (const float*)d_in[6];
    float* out = (float*)d_out;

    const int nNodes = in_sizes[0] / DFEAT;    // 100000
    const int nE     = in_sizes[1];            // 3200000

    // Workspace layout (all 256B-aligned):
    //   conv    : nNodes*128 f32   (51.2 MB)
    //   edge_src: nE ints          (12.8 MB)
    //   counts  : nNodes ints
    //   offsets : nNodes+1 ints
    //   cursor  : nNodes ints
    char* ws = (char*)d_ws;
    float* conv    = (float*)ws;                       ws += (size_t)nNodes * DFEAT * 4;
    int* edge_src  = (int*)ws;                         ws += (size_t)nE * 4;
    int* counts    = (int*)ws;                         ws += (size_t)(nNodes + 64) * 4;
    int* offsets   = (int*)ws;                         ws += (size_t)(nNodes + 64) * 4;
    int* cursor    = (int*)ws;

    // 1) CSR build
    hipMemsetAsync(counts, 0, (size_t)nNodes * 4, stream);
    hist_kernel<<<(nE + 255) / 256, 256, 0, stream>>>(refA, counts, nE);
    scan_offsets<<<1, SCAN_THREADS, 0, stream>>>(counts, offsets, cursor, nNodes);
    build_csr<<<(nE + 255) / 256, 256, 0, stream>>>(refA, refB, cursor, edge_src, nE);

    // 2) pull aggregation: conv = X + segment_sum(X[src] by dst)
    long long nThr = (long long)nNodes * 32;
    aggregate<<<(int)((nThr + 255) / 256), 256, 0, stream>>>(X, offsets, edge_src,
                                                             conv, nNodes);

    // 3) conv = relu(conv @ w1 + b1)   (in-place)
    int gBlocks = (nNodes + 63) / 64;
    gemm_relu<<<gBlocks, 256, 0, stream>>>(conv, w1, b1, conv, nNodes);

    // 4) out = relu(conv @ w2 + b2)
    gemm_relu<<<gBlocks, 256, 0, stream>>>(conv, w2, b2, out, nNodes);
}

// Round 3
// 697.538 us; speedup vs baseline: 7.9596x; 1.4727x over previous
//
#include <hip/hip_runtime.h>
#include <hip/hip_bf16.h>

#define NNODES 100000
#define DFEAT 128
#define NXCD 8

// ---------------------------------------------------------------------------
// CSR stage 1: per-destination edge counts, XCD-striped.
// blockIdx % 8 -> XCD (measured round-robin, m09). Each XCD scans all edges
// but only counts destinations in its own node stripe, so the count atomics
// stay in that XCD's L2 (no cross-XCD dirty-line ping-pong). Correct for ANY
// block->XCD mapping: stripes partition nodes, each edge counted exactly once.
// ---------------------------------------------------------------------------
__global__ __launch_bounds__(256)
void hist_xcd(const int* __restrict__ dst, int* __restrict__ counts,
              int nE, int nNodes) {
    const int xcd    = blockIdx.x & (NXCD - 1);
    const int blk    = blockIdx.x >> 3;
    const int nblk   = gridDim.x >> 3;
    const int stripe = (nNodes + NXCD - 1) >> 3;
    const int lo = xcd * stripe;
    const int hi = min(lo + stripe, nNodes);
    for (long long i = (long long)blk * 256 + threadIdx.x; i < nE;
         i += (long long)nblk * 256) {
        int d = dst[i];
        if (d >= lo && d < hi) atomicAdd(&counts[d], 1);
    }
}

// ---------------------------------------------------------------------------
// CSR stage 2a: per-block partial sums of counts (391 blocks x 256)
// ---------------------------------------------------------------------------
__global__ __launch_bounds__(256)
void partial_sums(const int* __restrict__ counts, int* __restrict__ bsum, int n) {
    __shared__ int tmp[4];
    int i = blockIdx.x * 256 + threadIdx.x;
    int v = (i < n) ? counts[i] : 0;
#pragma unroll
    for (int d = 32; d; d >>= 1) v += __shfl_down(v, d, 64);
    if ((threadIdx.x & 63) == 0) tmp[threadIdx.x >> 6] = v;
    __syncthreads();
    if (threadIdx.x == 0)
        bsum[blockIdx.x] = tmp[0] + tmp[1] + tmp[2] + tmp[3];
}

// ---------------------------------------------------------------------------
// CSR stage 2b: exclusive scan of block sums (1 block, 512 threads)
// ---------------------------------------------------------------------------
__global__ __launch_bounds__(512)
void scan_bsums(const int* __restrict__ bsum, int* __restrict__ bbase, int nb) {
    __shared__ int part[512];
    const int tid = threadIdx.x;
    const int chunk = (nb + 511) / 512;
    const int lo = min(tid * chunk, nb);
    const int hi = min(lo + chunk, nb);
    int s = 0;
    for (int i = lo; i < hi; ++i) s += bsum[i];
    part[tid] = s;
    __syncthreads();
    for (int d = 1; d < 512; d <<= 1) {
        int t = (tid >= d) ? part[tid - d] : 0;
        __syncthreads();
        part[tid] += t;
        __syncthreads();
    }
    int run = (tid == 0) ? 0 : part[tid - 1];
    for (int i = lo; i < hi; ++i) { bbase[i] = run; run += bsum[i]; }
}

// ---------------------------------------------------------------------------
// CSR stage 2c: offsets[i] = bbase[block] + block-local exclusive scan
// ---------------------------------------------------------------------------
__global__ __launch_bounds__(256)
void write_offsets(const int* __restrict__ counts, const int* __restrict__ bbase,
                   int* __restrict__ offsets, int* __restrict__ cursor, int n) {
    __shared__ int tmp[256];
    const int tid = threadIdx.x;
    const int i = blockIdx.x * 256 + tid;
    int v = (i < n) ? counts[i] : 0;
    tmp[tid] = v;
    __syncthreads();
    for (int d = 1; d < 256; d <<= 1) {
        int t = (tid >= d) ? tmp[tid - d] : 0;
        __syncthreads();
        tmp[tid] += t;
        __syncthreads();
    }
    int off = bbase[blockIdx.x] + tmp[tid] - v;   // exclusive
    if (i < n) { offsets[i] = off; cursor[i] = off; }
    if (i == n - 1) offsets[n] = off + v;         // total = nE
}

// ---------------------------------------------------------------------------
// CSR stage 3: scatter edge src ids, XCD-striped (same stripe scheme as hist).
// Each XCD's writes land in its own contiguous 1/8 slice of edge_src and its
// own cursor slice -> lines fill fully in its L2, write back once.
// ---------------------------------------------------------------------------
__global__ __launch_bounds__(256)
void build_csr_xcd(const int* __restrict__ dst, const int* __restrict__ src,
                   int* __restrict__ cursor, int* __restrict__ edge_src,
                   int nE, int nNodes) {
    const int xcd    = blockIdx.x & (NXCD - 1);
    const int blk    = blockIdx.x >> 3;
    const int nblk   = gridDim.x >> 3;
    const int stripe = (nNodes + NXCD - 1) >> 3;
    const int lo = xcd * stripe;
    const int hi = min(lo + stripe, nNodes);
    for (long long i = (long long)blk * 256 + threadIdx.x; i < nE;
         i += (long long)nblk * 256) {
        int d = dst[i];
        if (d >= lo && d < hi) {
            int pos = atomicAdd(&cursor[d], 1);
            edge_src[pos] = src[i];
        }
    }
}

// ---------------------------------------------------------------------------
// Pull aggregation: conv[n] = X[n] + sum_{e in csr(n)} X[edge_src[e]]
// 32 lanes per node (float4/lane covers 128 floats); 4-edge unroll for MLP.
// ---------------------------------------------------------------------------
__global__ __launch_bounds__(256)
void aggregate(const float* __restrict__ X, const int* __restrict__ offsets,
               const int* __restrict__ edge_src, float* __restrict__ conv,
               int nNodes) {
    long long g = (long long)blockIdx.x * blockDim.x + threadIdx.x;
    int node = (int)(g >> 5);
    if (node >= nNodes) return;
    int lane = (int)(g & 31);

    const float4* __restrict__ Xv = (const float4*)X;
    float4 acc = Xv[(size_t)node * 32 + lane];

    int e   = offsets[node];
    int end = offsets[node + 1];

    for (; e + 4 <= end; e += 4) {
        int s0 = edge_src[e + 0];
        int s1 = edge_src[e + 1];
        int s2 = edge_src[e + 2];
        int s3 = edge_src[e + 3];
        float4 v0 = Xv[(size_t)s0 * 32 + lane];
        float4 v1 = Xv[(size_t)s1 * 32 + lane];
        float4 v2 = Xv[(size_t)s2 * 32 + lane];
        float4 v3 = Xv[(size_t)s3 * 32 + lane];
        acc.x += v0.x; acc.y += v0.y; acc.z += v0.z; acc.w += v0.w;
        acc.x += v1.x; acc.y += v1.y; acc.z += v1.z; acc.w += v1.w;
        acc.x += v2.x; acc.y += v2.y; acc.z += v2.z; acc.w += v2.w;
        acc.x += v3.x; acc.y += v3.y; acc.z += v3.z; acc.w += v3.w;
    }
    for (; e < end; ++e) {
        int s = edge_src[e];
        float4 v = Xv[(size_t)s * 32 + lane];
        acc.x += v.x; acc.y += v.y; acc.z += v.z; acc.w += v.w;
    }

    ((float4*)conv)[(size_t)node * 32 + lane] = acc;
}

// ---------------------------------------------------------------------------
// C = relu(A @ W + b), A:[N,128] f32, W:[128,128], b:[128]
// 64 rows per block, 256 threads, per-thread 4x8 register tile.
// A staged to LDS before any write => safe in-place (C == A).
// ---------------------------------------------------------------------------
__global__ __launch_bounds__(256, 1)
void gemm_relu(const float* __restrict__ A, const float* __restrict__ W,
               const float* __restrict__ bias, float* __restrict__ C, int N) {
    __shared__ float sA[64][132];
    __shared__ float sW[128][128];
    const int tid  = threadIdx.x;
    const int row0 = blockIdx.x * 64;

    for (int i = tid; i < 128 * 32; i += 256) {
        int r = i >> 5, c = (i & 31) << 2;
        *(float4*)&sW[r][c] = *(const float4*)&W[r * 128 + c];
    }
    for (int i = tid; i < 64 * 32; i += 256) {
        int r = i >> 5, c = (i & 31) << 2;
        float4 v = make_float4(0.f, 0.f, 0.f, 0.f);
        if (row0 + r < N) v = *(const float4*)&A[(size_t)(row0 + r) * 128 + c];
        *(float4*)&sA[r][c] = v;
    }
    __syncthreads();

    const int tx = tid & 15;
    const int ty = tid >> 4;
    float acc[4][8];
#pragma unroll
    for (int i = 0; i < 4; ++i)
#pragma unroll
        for (int j = 0; j < 8; ++j) acc[i][j] = 0.f;

#pragma unroll 8
    for (int k = 0; k < 128; ++k) {
        float4 w0 = *(const float4*)&sW[k][tx * 8];
        float4 w1 = *(const float4*)&sW[k][tx * 8 + 4];
        float a[4];
#pragma unroll
        for (int i = 0; i < 4; ++i) a[i] = sA[ty * 4 + i][k];
#pragma unroll
        for (int i = 0; i < 4; ++i) {
            acc[i][0] += a[i] * w0.x;
            acc[i][1] += a[i] * w0.y;
            acc[i][2] += a[i] * w0.z;
            acc[i][3] += a[i] * w0.w;
            acc[i][4] += a[i] * w1.x;
            acc[i][5] += a[i] * w1.y;
            acc[i][6] += a[i] * w1.z;
            acc[i][7] += a[i] * w1.w;
        }
    }

    float b[8];
#pragma unroll
    for (int j = 0; j < 8; ++j) b[j] = bias[tx * 8 + j];

#pragma unroll
    for (int i = 0; i < 4; ++i) {
        int row = row0 + ty * 4 + i;
        if (row < N) {
            float4 o0, o1;
            o0.x = fmaxf(acc[i][0] + b[0], 0.f);
            o0.y = fmaxf(acc[i][1] + b[1], 0.f);
            o0.z = fmaxf(acc[i][2] + b[2], 0.f);
            o0.w = fmaxf(acc[i][3] + b[3], 0.f);
            o1.x = fmaxf(acc[i][4] + b[4], 0.f);
            o1.y = fmaxf(acc[i][5] + b[5], 0.f);
            o1.z = fmaxf(acc[i][6] + b[6], 0.f);
            o1.w = fmaxf(acc[i][7] + b[7], 0.f);
            *(float4*)&C[(size_t)row * 128 + tx * 8]     = o0;
            *(float4*)&C[(size_t)row * 128 + tx * 8 + 4] = o1;
        }
    }
}

// ---------------------------------------------------------------------------
extern "C" void kernel_launch(void* const* d_in, const int* in_sizes, int n_in,
                              void* d_out, int out_size, void* d_ws, size_t ws_size,
                              hipStream_t stream) {
    const float* X    = (const float*)d_in[0];
    const int*   refA = (const int*)d_in[1];   // dst per edge
    const int*   refB = (const int*)d_in[2];   // src per edge
    const float* w1   = (const float*)d_in[3];
    const float* b1   = (const float*)d_in[4];
    const float* w2   = (const float*)d_in[5];
    const float* b2   = (const float*)d_in[6];
    float* out = (float*)d_out;

    const int nNodes = in_sizes[0] / DFEAT;    // 100000
    const int nE     = in_sizes[1];            // 3200000
    const int nb     = (nNodes + 255) / 256;   // 391 scan blocks

    // Workspace layout:
    //   conv    : nNodes*128 f32   (51.2 MB)
    //   edge_src: nE ints          (12.8 MB)
    //   counts / offsets / cursor : ~nNodes ints each
    //   bsum / bbase : nb ints each
    char* ws = (char*)d_ws;
    float* conv   = (float*)ws;   ws += (size_t)nNodes * DFEAT * 4;
    int* edge_src = (int*)ws;     ws += (size_t)nE * 4;
    int* counts   = (int*)ws;     ws += (size_t)(nNodes + 64) * 4;
    int* offsets  = (int*)ws;     ws += (size_t)(nNodes + 64) * 4;
    int* cursor   = (int*)ws;     ws += (size_t)(nNodes + 64) * 4;
    int* bsum     = (int*)ws;     ws += (size_t)(nb + 64) * 4;
    int* bbase    = (int*)ws;

    // 1) CSR build (XCD-striped hist/scatter + hierarchical scan)
    hipMemsetAsync(counts, 0, (size_t)nNodes * 4, stream);
    hist_xcd<<<2048, 256, 0, stream>>>(refA, counts, nE, nNodes);
    partial_sums<<<nb, 256, 0, stream>>>(counts, bsum, nNodes);
    scan_bsums<<<1, 512, 0, stream>>>(bsum, bbase, nb);
    write_offsets<<<nb, 256, 0, stream>>>(counts, bbase, offsets, cursor, nNodes);
    build_csr_xcd<<<2048, 256, 0, stream>>>(refA, refB, cursor, edge_src, nE, nNodes);

    // 2) pull aggregation: conv = X + segment_sum(X[src] by dst)
    long long nThr = (long long)nNodes * 32;
    aggregate<<<(int)((nThr + 255) / 256), 256, 0, stream>>>(X, offsets, edge_src,
                                                             conv, nNodes);

    // 3) conv = relu(conv @ w1 + b1)   (in-place)
    int gBlocks = (nNodes + 63) / 64;
    gemm_relu<<<gBlocks, 256, 0, stream>>>(conv, w1, b1, conv, nNodes);

    // 4) out = relu(conv @ w2 + b2)
    gemm_relu<<<gBlocks, 256, 0, stream>>>(conv, w2, b2, out, nNodes);
}

// Round 5
// 451.040 us; speedup vs baseline: 12.3096x; 1.5465x over previous
//
#include <hip/hip_runtime.h>
#include <hip/hip_bf16.h>

#define NNODES 100000
#define DFEAT 128
#define NXCD 8

typedef short bf16x8 __attribute__((ext_vector_type(8)));
typedef float f32x4  __attribute__((ext_vector_type(4)));

__device__ __forceinline__ unsigned short f2bf(float f) {
    unsigned u = __builtin_bit_cast(unsigned, f);
    return (unsigned short)((u + 0x7fffu + ((u >> 16) & 1u)) >> 16);
}

// ---------------------------------------------------------------------------
// X fp32 -> bf16 (packed), 8 elems/thread
// ---------------------------------------------------------------------------
__global__ __launch_bounds__(256)
void x2bf_kernel(const float4* __restrict__ X, uint4* __restrict__ Xb, int n8) {
    int i = blockIdx.x * 256 + threadIdx.x;
    if (i >= n8) return;
    float4 a = X[2 * i], b = X[2 * i + 1];
    uint4 o;
    o.x = f2bf(a.x) | ((unsigned)f2bf(a.y) << 16);
    o.y = f2bf(a.z) | ((unsigned)f2bf(a.w) << 16);
    o.z = f2bf(b.x) | ((unsigned)f2bf(b.y) << 16);
    o.w = f2bf(b.z) | ((unsigned)f2bf(b.w) << 16);
    Xb[i] = o;
}

// ---------------------------------------------------------------------------
// W[k][n] fp32 -> Wt[n][k] bf16, both weight matrices in one launch (32768 el)
// ---------------------------------------------------------------------------
__global__ __launch_bounds__(256)
void wprep(const float* __restrict__ w1, const float* __restrict__ w2,
           unsigned short* __restrict__ w1t, unsigned short* __restrict__ w2t) {
    int i = blockIdx.x * 256 + threadIdx.x;           // 0..32767
    const float* w = (i < 16384) ? w1 : w2;
    unsigned short* o = (i < 16384) ? w1t : w2t;
    int j = i & 16383;
    int n = j >> 7, k = j & 127;
    o[n * 128 + k] = f2bf(w[k * 128 + n]);
}

// ---------------------------------------------------------------------------
// CSR stage 1: per-destination edge counts, XCD-striped (see R2 notes)
// ---------------------------------------------------------------------------
__global__ __launch_bounds__(256)
void hist_xcd(const int* __restrict__ dst, int* __restrict__ counts,
              int nE, int nNodes) {
    const int xcd    = blockIdx.x & (NXCD - 1);
    const int blk    = blockIdx.x >> 3;
    const int nblk   = gridDim.x >> 3;
    const int stripe = (nNodes + NXCD - 1) >> 3;
    const int lo = xcd * stripe;
    const int hi = min(lo + stripe, nNodes);
    for (long long i = (long long)blk * 256 + threadIdx.x; i < nE;
         i += (long long)nblk * 256) {
        int d = dst[i];
        if (d >= lo && d < hi) atomicAdd(&counts[d], 1);
    }
}

__global__ __launch_bounds__(256)
void partial_sums(const int* __restrict__ counts, int* __restrict__ bsum, int n) {
    __shared__ int tmp[4];
    int i = blockIdx.x * 256 + threadIdx.x;
    int v = (i < n) ? counts[i] : 0;
#pragma unroll
    for (int d = 32; d; d >>= 1) v += __shfl_down(v, d, 64);
    if ((threadIdx.x & 63) == 0) tmp[threadIdx.x >> 6] = v;
    __syncthreads();
    if (threadIdx.x == 0)
        bsum[blockIdx.x] = tmp[0] + tmp[1] + tmp[2] + tmp[3];
}

__global__ __launch_bounds__(512)
void scan_bsums(const int* __restrict__ bsum, int* __restrict__ bbase, int nb) {
    __shared__ int part[512];
    const int tid = threadIdx.x;
    const int chunk = (nb + 511) / 512;
    const int lo = min(tid * chunk, nb);
    const int hi = min(lo + chunk, nb);
    int s = 0;
    for (int i = lo; i < hi; ++i) s += bsum[i];
    part[tid] = s;
    __syncthreads();
    for (int d = 1; d < 512; d <<= 1) {
        int t = (tid >= d) ? part[tid - d] : 0;
        __syncthreads();
        part[tid] += t;
        __syncthreads();
    }
    int run = (tid == 0) ? 0 : part[tid - 1];
    for (int i = lo; i < hi; ++i) { bbase[i] = run; run += bsum[i]; }
}

__global__ __launch_bounds__(256)
void write_offsets(const int* __restrict__ counts, const int* __restrict__ bbase,
                   int* __restrict__ offsets, int* __restrict__ cursor, int n) {
    __shared__ int tmp[256];
    const int tid = threadIdx.x;
    const int i = blockIdx.x * 256 + tid;
    int v = (i < n) ? counts[i] : 0;
    tmp[tid] = v;
    __syncthreads();
    for (int d = 1; d < 256; d <<= 1) {
        int t = (tid >= d) ? tmp[tid - d] : 0;
        __syncthreads();
        tmp[tid] += t;
        __syncthreads();
    }
    int off = bbase[blockIdx.x] + tmp[tid] - v;
    if (i < n) { offsets[i] = off; cursor[i] = off; }
    if (i == n - 1) offsets[n] = off + v;
}

__global__ __launch_bounds__(256)
void build_csr_xcd(const int* __restrict__ dst, const int* __restrict__ src,
                   int* __restrict__ cursor, int* __restrict__ edge_src,
                   int nE, int nNodes) {
    const int xcd    = blockIdx.x & (NXCD - 1);
    const int blk    = blockIdx.x >> 3;
    const int nblk   = gridDim.x >> 3;
    const int stripe = (nNodes + NXCD - 1) >> 3;
    const int lo = xcd * stripe;
    const int hi = min(lo + stripe, nNodes);
    for (long long i = (long long)blk * 256 + threadIdx.x; i < nE;
         i += (long long)nblk * 256) {
        int d = dst[i];
        if (d >= lo && d < hi) {
            int pos = atomicAdd(&cursor[d], 1);
            edge_src[pos] = src[i];
        }
    }
}

// ---------------------------------------------------------------------------
// Pull aggregation in bf16: convb[n] = bf16( Xb[n] + sum_e Xb[edge_src[e]] )
// 16 lanes per node, 16 B (8 bf16) per lane, fp32 accumulate.
// ---------------------------------------------------------------------------
__device__ __forceinline__ void bfadd(float* acc, uint4 v) {
    acc[0] += __builtin_bit_cast(float, v.x << 16);
    acc[1] += __builtin_bit_cast(float, v.x & 0xffff0000u);
    acc[2] += __builtin_bit_cast(float, v.y << 16);
    acc[3] += __builtin_bit_cast(float, v.y & 0xffff0000u);
    acc[4] += __builtin_bit_cast(float, v.z << 16);
    acc[5] += __builtin_bit_cast(float, v.z & 0xffff0000u);
    acc[6] += __builtin_bit_cast(float, v.w << 16);
    acc[7] += __builtin_bit_cast(float, v.w & 0xffff0000u);
}

__global__ __launch_bounds__(256)
void aggregate_bf(const uint4* __restrict__ Xb, const int* __restrict__ offsets,
                  const int* __restrict__ edge_src, uint4* __restrict__ convb,
                  int nNodes) {
    long long g = (long long)blockIdx.x * 256 + threadIdx.x;
    int node = (int)(g >> 4);
    if (node >= nNodes) return;
    int lane = (int)(g & 15);

    float acc[8];
    {
        uint4 v = Xb[(size_t)node * 16 + lane];
#pragma unroll
        for (int j = 0; j < 8; ++j) acc[j] = 0.f;
        bfadd(acc, v);
    }

    int e   = offsets[node];
    int end = offsets[node + 1];

    for (; e + 4 <= end; e += 4) {
        int s0 = edge_src[e + 0];
        int s1 = edge_src[e + 1];
        int s2 = edge_src[e + 2];
        int s3 = edge_src[e + 3];
        uint4 v0 = Xb[(size_t)s0 * 16 + lane];
        uint4 v1 = Xb[(size_t)s1 * 16 + lane];
        uint4 v2 = Xb[(size_t)s2 * 16 + lane];
        uint4 v3 = Xb[(size_t)s3 * 16 + lane];
        bfadd(acc, v0); bfadd(acc, v1); bfadd(acc, v2); bfadd(acc, v3);
    }
    for (; e < end; ++e) {
        uint4 v = Xb[(size_t)edge_src[e] * 16 + lane];
        bfadd(acc, v);
    }

    uint4 o;
    o.x = f2bf(acc[0]) | ((unsigned)f2bf(acc[1]) << 16);
    o.y = f2bf(acc[2]) | ((unsigned)f2bf(acc[3]) << 16);
    o.z = f2bf(acc[4]) | ((unsigned)f2bf(acc[5]) << 16);
    o.w = f2bf(acc[6]) | ((unsigned)f2bf(acc[7]) << 16);
    convb[(size_t)node * 16 + lane] = o;
}

// ---------------------------------------------------------------------------
// Fused MLP: out = relu(relu(conv @ W1 + b1) @ W2 + b2), bf16 MFMA, fp32 acc.
// 128-node tile per block, 256 threads = 4 waves, each wave owns 32 rows.
// A/B frag: lane l -> row/col = l%16, k = (l>>4)*8 + e (same rule both sides
// => k-permutation-invariant). C/D (m89-verified): col=lane&15, row=(lane>>4)*4+reg.
// LDS rows padded to 136 bf16 (272 B): 16B-aligned b128 reads.
// ---------------------------------------------------------------------------
#define TM 128

__global__ __launch_bounds__(256, 1)
void mlp_fused(const unsigned short* __restrict__ convb,
               const unsigned short* __restrict__ w1t, const float* __restrict__ b1,
               const unsigned short* __restrict__ w2t, const float* __restrict__ b2,
               float* __restrict__ out, int N) {
    __shared__ unsigned short sA[TM][136];
    __shared__ unsigned short sW[128][136];
    __shared__ unsigned short sH[TM][136];

    const int tid  = threadIdx.x;
    const int row0 = blockIdx.x * TM;

    // stage A tile (guarded) and W1^T
    for (int i = tid; i < TM * 16; i += 256) {
        int r = i >> 4, c = i & 15;
        uint4 v = make_uint4(0, 0, 0, 0);
        if (row0 + r < N) v = ((const uint4*)convb)[(size_t)(row0 + r) * 16 + c];
        *(uint4*)&sA[r][c * 8] = v;
    }
    for (int i = tid; i < 128 * 16; i += 256) {
        int r = i >> 4, c = i & 15;
        *(uint4*)&sW[r][c * 8] = ((const uint4*)w1t)[r * 16 + c];
    }
    __syncthreads();

    const int lane = tid & 63;
    const int lrow = lane & 15;
    const int kgrp = lane >> 4;
    const int m0   = (tid >> 6) * 32;

    float bias[8];
#pragma unroll
    for (int nf = 0; nf < 8; ++nf) bias[nf] = b1[nf * 16 + lrow];

    f32x4 acc[2][8] = {};
#pragma unroll
    for (int kk = 0; kk < 128; kk += 32) {
        bf16x8 a0 = *(const bf16x8*)&sA[m0 + lrow][kk + kgrp * 8];
        bf16x8 a1 = *(const bf16x8*)&sA[m0 + 16 + lrow][kk + kgrp * 8];
#pragma unroll
        for (int nf = 0; nf < 8; ++nf) {
            bf16x8 b = *(const bf16x8*)&sW[nf * 16 + lrow][kk + kgrp * 8];
            acc[0][nf] = __builtin_amdgcn_mfma_f32_16x16x32_bf16(a0, b, acc[0][nf], 0, 0, 0);
            acc[1][nf] = __builtin_amdgcn_mfma_f32_16x16x32_bf16(a1, b, acc[1][nf], 0, 0, 0);
        }
    }

    // layer-1 epilogue: relu -> bf16 -> sH (each wave writes only its own rows)
#pragma unroll
    for (int mf = 0; mf < 2; ++mf)
#pragma unroll
        for (int nf = 0; nf < 8; ++nf)
#pragma unroll
            for (int r = 0; r < 4; ++r) {
                int row = m0 + mf * 16 + kgrp * 4 + r;
                int col = nf * 16 + lrow;
                float h = fmaxf(acc[mf][nf][r] + bias[nf], 0.f);
                sH[row][col] = f2bf(h);
            }

    __syncthreads();   // all waves done reading sW (and sH complete)

    // reload sW <- W2^T
    for (int i = tid; i < 128 * 16; i += 256) {
        int r = i >> 4, c = i & 15;
        *(uint4*)&sW[r][c * 8] = ((const uint4*)w2t)[r * 16 + c];
    }
#pragma unroll
    for (int nf = 0; nf < 8; ++nf) bias[nf] = b2[nf * 16 + lrow];
#pragma unroll
    for (int mf = 0; mf < 2; ++mf)
#pragma unroll
        for (int nf = 0; nf < 8; ++nf) acc[mf][nf] = (f32x4){0.f, 0.f, 0.f, 0.f};
    __syncthreads();

#pragma unroll
    for (int kk = 0; kk < 128; kk += 32) {
        bf16x8 a0 = *(const bf16x8*)&sH[m0 + lrow][kk + kgrp * 8];
        bf16x8 a1 = *(const bf16x8*)&sH[m0 + 16 + lrow][kk + kgrp * 8];
#pragma unroll
        for (int nf = 0; nf < 8; ++nf) {
            bf16x8 b = *(const bf16x8*)&sW[nf * 16 + lrow][kk + kgrp * 8];
            acc[0][nf] = __builtin_amdgcn_mfma_f32_16x16x32_bf16(a0, b, acc[0][nf], 0, 0, 0);
            acc[1][nf] = __builtin_amdgcn_mfma_f32_16x16x32_bf16(a1, b, acc[1][nf], 0, 0, 0);
        }
    }

    // layer-2 epilogue: relu -> fp32 global
#pragma unroll
    for (int mf = 0; mf < 2; ++mf)
#pragma unroll
        for (int nf = 0; nf < 8; ++nf)
#pragma unroll
            for (int r = 0; r < 4; ++r) {
                int row = row0 + m0 + mf * 16 + kgrp * 4 + r;
                int col = nf * 16 + lrow;
                if (row < N)
                    out[(size_t)row * 128 + col] = fmaxf(acc[mf][nf][r] + bias[nf], 0.f);
            }
}

// ---------------------------------------------------------------------------
extern "C" void kernel_launch(void* const* d_in, const int* in_sizes, int n_in,
                              void* d_out, int out_size, void* d_ws, size_t ws_size,
                              hipStream_t stream) {
    const float* X    = (const float*)d_in[0];
    const int*   refA = (const int*)d_in[1];   // dst per edge
    const int*   refB = (const int*)d_in[2];   // src per edge
    const float* w1   = (const float*)d_in[3];
    const float* b1   = (const float*)d_in[4];
    const float* w2   = (const float*)d_in[5];
    const float* b2   = (const float*)d_in[6];
    float* out = (float*)d_out;

    const int nNodes = in_sizes[0] / DFEAT;    // 100000
    const int nE     = in_sizes[1];            // 3200000
    const int nb     = (nNodes + 255) / 256;

    // Workspace layout:
    //   Xb      : nNodes*128 bf16  (25.6 MB)
    //   convb   : nNodes*128 bf16  (25.6 MB)
    //   edge_src: nE ints          (12.8 MB)
    //   w1t,w2t : 16384 bf16 each
    //   counts / offsets / cursor / bsum / bbase
    char* ws = (char*)d_ws;
    unsigned short* Xb    = (unsigned short*)ws;  ws += (size_t)nNodes * DFEAT * 2;
    unsigned short* convb = (unsigned short*)ws;  ws += (size_t)nNodes * DFEAT * 2;
    int* edge_src = (int*)ws;                     ws += (size_t)nE * 4;
    unsigned short* w1t = (unsigned short*)ws;    ws += 16384 * 2;
    unsigned short* w2t = (unsigned short*)ws;    ws += 16384 * 2;
    int* counts   = (int*)ws;                     ws += (size_t)(nNodes + 64) * 4;
    int* offsets  = (int*)ws;                     ws += (size_t)(nNodes + 64) * 4;
    int* cursor   = (int*)ws;                     ws += (size_t)(nNodes + 64) * 4;
    int* bsum     = (int*)ws;                     ws += (size_t)(nb + 64) * 4;
    int* bbase    = (int*)ws;

    // 0) precision prep
    int n8 = nNodes * DFEAT / 8;
    x2bf_kernel<<<(n8 + 255) / 256, 256, 0, stream>>>((const float4*)X, (uint4*)Xb, n8);
    wprep<<<128, 256, 0, stream>>>(w1, w2, w1t, w2t);

    // 1) CSR build (XCD-striped hist/scatter + hierarchical scan)
    hipMemsetAsync(counts, 0, (size_t)nNodes * 4, stream);
    hist_xcd<<<2048, 256, 0, stream>>>(refA, counts, nE, nNodes);
    partial_sums<<<nb, 256, 0, stream>>>(counts, bsum, nNodes);
    scan_bsums<<<1, 512, 0, stream>>>(bsum, bbase, nb);
    write_offsets<<<nb, 256, 0, stream>>>(counts, bbase, offsets, cursor, nNodes);
    build_csr_xcd<<<2048, 256, 0, stream>>>(refA, refB, cursor, edge_src, nE, nNodes);

    // 2) pull aggregation (bf16 gather, fp32 accumulate)
    long long nThr = (long long)nNodes * 16;
    aggregate_bf<<<(int)((nThr + 255) / 256), 256, 0, stream>>>(
        (const uint4*)Xb, offsets, edge_src, (uint4*)convb, nNodes);

    // 3+4) fused MLP via bf16 MFMA
    int mBlocks = (nNodes + TM - 1) / TM;
    mlp_fused<<<mBlocks, 256, 0, stream>>>(convb, w1t, b1, w2t, b2, out, nNodes);
}